// Round 7
// baseline (147.412 us; speedup 1.0000x reference)
//
#include <hip/hip_runtime.h>
#include <hip/hip_bf16.h>

#define BATCH 4
#define NROW  4096
#define DIM   256
#define BM 128
#define BN 128
#define BK 64

#define C_NEG (-0.72134752f)   // -0.5*log2(e)
#define K2    (1.44269504f)    // log2(e) (coefficient on xy)

typedef __attribute__((ext_vector_type(8))) short frag_ab;  // 8 bf16
typedef __attribute__((ext_vector_type(4))) float frag_cd;  // 4 f32

__device__ __forceinline__ short f2bf(float f) {
    __hip_bfloat16 h = __float2bfloat16(f);
    short s;
    __builtin_memcpy(&s, &h, 2);
    return s;
}

__device__ __forceinline__ frag_ab pack8(float4 a, float4 b) {
    frag_ab v;
    v[0] = f2bf(a.x); v[1] = f2bf(a.y); v[2] = f2bf(a.z); v[3] = f2bf(a.w);
    v[4] = f2bf(b.x); v[5] = f2bf(b.y); v[6] = f2bf(b.z); v[7] = f2bf(b.w);
    return v;
}

// ---------------------------------------------------------------------------
// FAST PATH kernel 1: fp32 -> bf16 copy of X,Y into ws + scaled row norms.
__global__ __launch_bounds__(256) void rbf_prep(const float* __restrict__ X,
                                                const float* __restrict__ Y,
                                                float* __restrict__ cx,
                                                float* __restrict__ cy,
                                                ushort* __restrict__ Xb,
                                                ushort* __restrict__ Yb) {
    const int lane = threadIdx.x & 63;
    const int wid0 = (int)(blockIdx.x * blockDim.x + threadIdx.x) >> 6;
    const int nw   = (int)(gridDim.x * blockDim.x) >> 6;
    const int total = 2 * BATCH * NROW;
    for (int row = wid0; row < total; row += nw) {
        const bool isX = row < BATCH * NROW;
        const int r = isX ? row : row - BATCH * NROW;
        const float* src = (isX ? X : Y) + (size_t)r * DIM;
        ushort* dst = (isX ? Xb : Yb) + (size_t)r * DIM;
        float4 v = ((const float4*)src)[lane];
        ushort4 o;
        o.x = (ushort)f2bf(v.x); o.y = (ushort)f2bf(v.y);
        o.z = (ushort)f2bf(v.z); o.w = (ushort)f2bf(v.w);
        ((ushort4*)dst)[lane] = o;
        float s = v.x * v.x + v.y * v.y + v.z * v.z + v.w * v.w;
        #pragma unroll
        for (int off = 32; off > 0; off >>= 1)
            s += __shfl_down(s, off, 64);
        if (lane == 0) (isX ? cx : cy)[r] = C_NEG * s;
    }
}

// ---------------------------------------------------------------------------
// FAST PATH kernel 2: NO-LDS variant. Each wave loads its MFMA fragments
// directly global->register (bf16 ws copy is L2-resident; each A-frag
// wave-instruction = 16 rows x 64B coalesced segments, lines reused across
// consecutive kk). Zero barriers, zero LDS -> all pipes overlap freely and
// the compiler software-pipelines the unrolled K-loop.
// Fragment indexing identical to the proven round-4 kernel:
//   af[i] = 16B at row (wr*64+i*16+(lane&15)), k = kk*32+(lane>>4)*8.
__global__ __launch_bounds__(256, 2) void rbf_main_fast(const ushort* __restrict__ Xb,
                                                        const ushort* __restrict__ Yb,
                                                        const float* __restrict__ cx,
                                                        const float* __restrict__ cy,
                                                        float* __restrict__ out) {
    // bijective XCD swizzle: 4096 blocks, 8 XCDs, 512 contiguous tiles each.
    const int n   = (int)blockIdx.x;
    const int swz = (n & 7) * (4096 / 8) + (n >> 3);
    const int b   = swz >> 10;
    const int rem = swz & 1023;
    const int row0 = (rem >> 5) * BM;
    const int col0 = (rem & 31) * BN;

    const int t    = threadIdx.x;
    const int lane = t & 63;
    const int wid  = t >> 6;
    const int wr   = wid >> 1;   // 0..1 : 64-row group
    const int wc   = wid & 1;    // 0..1 : 64-col group

    const ushort* Xw = Xb + (size_t)b * NROW * DIM;
    const ushort* Yw = Yb + (size_t)b * NROW * DIM;

    // per-lane fragment base pointers
    const ushort* Abase = Xw + (size_t)(row0 + wr * 64 + (lane & 15)) * DIM + ((lane >> 4) << 3);
    const ushort* Bbase = Yw + (size_t)(col0 + wc * 64 + (lane & 15)) * DIM + ((lane >> 4) << 3);

    frag_cd acc[4][4];
    #pragma unroll
    for (int i = 0; i < 4; ++i)
        #pragma unroll
        for (int j = 0; j < 4; ++j)
            acc[i][j] = (frag_cd)0.0f;

    #pragma unroll
    for (int kk = 0; kk < 8; ++kk) {           // K = 8 x 32
        frag_ab af[4], bfr[4];
        #pragma unroll
        for (int i = 0; i < 4; ++i)
            af[i] = *(const frag_ab*)(Abase + (size_t)i * 16 * DIM + kk * 32);
        #pragma unroll
        for (int j = 0; j < 4; ++j)
            bfr[j] = *(const frag_ab*)(Bbase + (size_t)j * 16 * DIM + kk * 32);
        #pragma unroll
        for (int i = 0; i < 4; ++i)
            #pragma unroll
            for (int j = 0; j < 4; ++j)
                acc[i][j] = __builtin_amdgcn_mfma_f32_16x16x32_bf16(af[i], bfr[j], acc[i][j], 0, 0, 0);
    }

    // epilogue (round-4 proven form): arg = cx + cy + log2e*xy ; min(exp2,1)
    const float* cxb = cx + (size_t)b * NROW;
    const float* cyb = cy + (size_t)b * NROW;
    float yv[4];
    #pragma unroll
    for (int j = 0; j < 4; ++j)
        yv[j] = cyb[col0 + wc * 64 + j * 16 + (lane & 15)];

    float* outb = out + (size_t)b * NROW * NROW;
    #pragma unroll
    for (int i = 0; i < 4; ++i) {
        const int rbase = row0 + wr * 64 + i * 16 + ((lane >> 4) << 2);
        const float4 xq = *(const float4*)(cxb + rbase);
        #pragma unroll
        for (int q = 0; q < 4; ++q) {
            const float xx = (q == 0) ? xq.x : (q == 1) ? xq.y : (q == 2) ? xq.z : xq.w;
            float* orow = outb + (size_t)(rbase + q) * NROW + col0 + wc * 64 + (lane & 15);
            #pragma unroll
            for (int j = 0; j < 4; ++j) {
                float arg = fmaf(K2, acc[i][j][q], xx + yv[j]);
                orow[j * 16] = fminf(__builtin_amdgcn_exp2f(arg), 1.0f);
            }
        }
    }
}

// ---------------------------------------------------------------------------
// FALLBACK (round-1, passing): used when ws_size < 16.1 MB.
__global__ __launch_bounds__(256) void rbf_norms_fb(const float* __restrict__ X,
                                                    const float* __restrict__ Y,
                                                    float* __restrict__ x2,
                                                    float* __restrict__ y2) {
    const int lane = threadIdx.x & 63;
    const int wid  = (int)(blockIdx.x * blockDim.x + threadIdx.x) >> 6;
    const int nw   = (int)(gridDim.x * blockDim.x) >> 6;
    const int total = 2 * BATCH * NROW;
    for (int row = wid; row < total; row += nw) {
        const float* src = (row < BATCH * NROW)
            ? X + (size_t)row * DIM
            : Y + (size_t)(row - BATCH * NROW) * DIM;
        float4 v = ((const float4*)src)[lane];
        float s = v.x * v.x + v.y * v.y + v.z * v.z + v.w * v.w;
        #pragma unroll
        for (int off = 32; off > 0; off >>= 1)
            s += __shfl_down(s, off, 64);
        if (lane == 0) {
            if (row < BATCH * NROW) x2[row] = s;
            else                    y2[row - BATCH * NROW] = s;
        }
    }
}

__global__ __launch_bounds__(256, 2) void rbf_main_fb(const float* __restrict__ X,
                                                      const float* __restrict__ Y,
                                                      const float* __restrict__ x2,
                                                      const float* __restrict__ y2,
                                                      float* __restrict__ out) {
    __shared__ short As[BM * BK];
    __shared__ short Bs[BN * BK];

    const int b    = blockIdx.z;
    const int row0 = blockIdx.y * BM;
    const int col0 = blockIdx.x * BN;

    const int t    = threadIdx.x;
    const int lane = t & 63;
    const int wid  = t >> 6;
    const int wr   = wid >> 1;
    const int wc   = wid & 1;

    const float* Xb = X + (size_t)b * NROW * DIM;
    const float* Yb = Y + (size_t)b * NROW * DIM;

    frag_cd acc[4][4];
    #pragma unroll
    for (int i = 0; i < 4; ++i)
        #pragma unroll
        for (int j = 0; j < 4; ++j)
            acc[i][j] = (frag_cd)0.0f;

    for (int kt = 0; kt < DIM / BK; ++kt) {
        const int k0 = kt * BK;
        float4 ra[4][2], rb[4][2];
        #pragma unroll
        for (int p = 0; p < 4; ++p) {
            const int c = t + p * 256;
            const int row = c >> 3, k8 = c & 7;
            const float4* sA = (const float4*)(Xb + (size_t)(row0 + row) * DIM + k0 + k8 * 8);
            ra[p][0] = sA[0]; ra[p][1] = sA[1];
            const float4* sB = (const float4*)(Yb + (size_t)(col0 + row) * DIM + k0 + k8 * 8);
            rb[p][0] = sB[0]; rb[p][1] = sB[1];
        }
        __syncthreads();
        #pragma unroll
        for (int p = 0; p < 4; ++p) {
            const int c = t + p * 256;
            const int row = c >> 3, k8 = c & 7;
            const int off = row * (BK * 2) + ((k8 ^ (row & 7)) * 16);
            *(frag_ab*)((char*)As + off) = pack8(ra[p][0], ra[p][1]);
            *(frag_ab*)((char*)Bs + off) = pack8(rb[p][0], rb[p][1]);
        }
        __syncthreads();
        #pragma unroll
        for (int kk = 0; kk < 2; ++kk) {
            frag_ab af[4], bfr[4];
            #pragma unroll
            for (int i = 0; i < 4; ++i) {
                const int row = wr * 64 + i * 16 + (lane & 15);
                const int ch  = (kk * 4 + (lane >> 4)) ^ (row & 7);
                af[i] = *(const frag_ab*)((const char*)As + row * (BK * 2) + ch * 16);
            }
            #pragma unroll
            for (int j = 0; j < 4; ++j) {
                const int row = wc * 64 + j * 16 + (lane & 15);
                const int ch  = (kk * 4 + (lane >> 4)) ^ (row & 7);
                bfr[j] = *(const frag_ab*)((const char*)Bs + row * (BK * 2) + ch * 16);
            }
            #pragma unroll
            for (int i = 0; i < 4; ++i)
                #pragma unroll
                for (int j = 0; j < 4; ++j)
                    acc[i][j] = __builtin_amdgcn_mfma_f32_16x16x32_bf16(af[i], bfr[j], acc[i][j], 0, 0, 0);
        }
    }

    const float* x2b = x2 + (size_t)b * NROW;
    const float* y2b = y2 + (size_t)b * NROW;
    float yv[4];
    #pragma unroll
    for (int j = 0; j < 4; ++j)
        yv[j] = y2b[col0 + wc * 64 + j * 16 + (lane & 15)];

    float* outb = out + (size_t)b * NROW * NROW;
    #pragma unroll
    for (int i = 0; i < 4; ++i) {
        const int rbase = row0 + wr * 64 + i * 16 + ((lane >> 4) << 2);
        const float4 xq = *(const float4*)(x2b + rbase);
        #pragma unroll
        for (int q = 0; q < 4; ++q) {
            const float xx = (q == 0) ? xq.x : (q == 1) ? xq.y : (q == 2) ? xq.z : xq.w;
            float* orow = outb + (size_t)(rbase + q) * NROW + col0 + wc * 64 + (lane & 15);
            #pragma unroll
            for (int j = 0; j < 4; ++j) {
                float d = xx + yv[j] - 2.0f * acc[i][j][q];
                d = fmaxf(d, 0.0f);
                orow[j * 16] = __expf(-0.5f * d);
            }
        }
    }
}

extern "C" void kernel_launch(void* const* d_in, const int* in_sizes, int n_in,
                              void* d_out, int out_size, void* d_ws, size_t ws_size,
                              hipStream_t stream) {
    const float* X = (const float*)d_in[0];
    const float* Y = (const float*)d_in[1];
    float* out = (float*)d_out;

    const size_t nrows = (size_t)BATCH * NROW;
    const size_t need  = 2 * nrows * sizeof(float) + 2 * nrows * DIM * sizeof(ushort);

    if (ws_size >= need) {
        float* cxp = (float*)d_ws;
        float* cyp = cxp + nrows;
        ushort* Xb = (ushort*)(cyp + nrows);
        ushort* Yb = Xb + nrows * DIM;
        rbf_prep<<<2048, 256, 0, stream>>>(X, Y, cxp, cyp, Xb, Yb);
        rbf_main_fast<<<4096, 256, 0, stream>>>(Xb, Yb, cxp, cyp, out);
    } else {
        float* x2 = (float*)d_ws;
        float* y2 = x2 + nrows;
        rbf_norms_fb<<<512, 256, 0, stream>>>(X, Y, x2, y2);
        rbf_main_fb<<<dim3(NROW / BN, NROW / BM, BATCH), 256, 0, stream>>>(X, Y, x2, y2, out);
    }
}

// Round 8
// 76.819 us; speedup vs baseline: 1.9189x; 1.9189x over previous
//
#include <hip/hip_runtime.h>
#include <hip/hip_bf16.h>

#define BATCH 4
#define NROW  4096
#define DIM   256
#define BM 128
#define BN 128
#define BK 64

#define C_NEG (-0.72134752f)   // -0.5*log2(e)
#define K2    (1.44269504f)    // log2(e) (coefficient on xy)

typedef __attribute__((ext_vector_type(8))) short frag_ab;  // 8 bf16
typedef __attribute__((ext_vector_type(4))) float frag_cd;  // 4 f32

__device__ __forceinline__ short f2bf(float f) {
    __hip_bfloat16 h = __float2bfloat16(f);
    short s;
    __builtin_memcpy(&s, &h, 2);
    return s;
}

__device__ __forceinline__ frag_ab pack8(float4 a, float4 b) {
    frag_ab v;
    v[0] = f2bf(a.x); v[1] = f2bf(a.y); v[2] = f2bf(a.z); v[3] = f2bf(a.w);
    v[4] = f2bf(b.x); v[5] = f2bf(b.y); v[6] = f2bf(b.z); v[7] = f2bf(b.w);
    return v;
}

// ---------------------------------------------------------------------------
// FAST PATH kernel 1: fp32 -> bf16 copy of X,Y into ws + scaled row norms.
__global__ __launch_bounds__(256) void rbf_prep(const float* __restrict__ X,
                                                const float* __restrict__ Y,
                                                float* __restrict__ cx,
                                                float* __restrict__ cy,
                                                ushort* __restrict__ Xb,
                                                ushort* __restrict__ Yb) {
    const int lane = threadIdx.x & 63;
    const int wid0 = (int)(blockIdx.x * blockDim.x + threadIdx.x) >> 6;
    const int nw   = (int)(gridDim.x * blockDim.x) >> 6;
    const int total = 2 * BATCH * NROW;
    for (int row = wid0; row < total; row += nw) {
        const bool isX = row < BATCH * NROW;
        const int r = isX ? row : row - BATCH * NROW;
        const float* src = (isX ? X : Y) + (size_t)r * DIM;
        ushort* dst = (isX ? Xb : Yb) + (size_t)r * DIM;
        float4 v = ((const float4*)src)[lane];
        ushort4 o;
        o.x = (ushort)f2bf(v.x); o.y = (ushort)f2bf(v.y);
        o.z = (ushort)f2bf(v.z); o.w = (ushort)f2bf(v.w);
        ((ushort4*)dst)[lane] = o;
        float s = v.x * v.x + v.y * v.y + v.z * v.z + v.w * v.w;
        #pragma unroll
        for (int off = 32; off > 0; off >>= 1)
            s += __shfl_down(s, off, 64);
        if (lane == 0) (isX ? cx : cy)[r] = C_NEG * s;
    }
}

// ---------------------------------------------------------------------------
// FAST PATH kernel 2: r4 structure + (a) software-pipelined LDS double buffer
// with ONE barrier per K-tile and loads(kt+1) issued BEFORE compute(kt), and
// (b) non-temporal output stores (output is write-once; keep it out of L2 so
// the bf16 inputs stay resident).
__global__ __launch_bounds__(256, 2) void rbf_main_fast(const ushort* __restrict__ Xb,
                                                        const ushort* __restrict__ Yb,
                                                        const float* __restrict__ cx,
                                                        const float* __restrict__ cy,
                                                        float* __restrict__ out) {
    __shared__ short As[2][BM * BK];   // 2 x 16 KB
    __shared__ short Bs[2][BN * BK];   // 2 x 16 KB

    // bijective XCD swizzle: 4096 blocks, 8 XCDs, 512 contiguous tiles each.
    const int n   = (int)blockIdx.x;
    const int swz = (n & 7) * (4096 / 8) + (n >> 3);
    const int b   = swz >> 10;
    const int rem = swz & 1023;
    const int row0 = (rem >> 5) * BM;
    const int col0 = (rem & 31) * BN;

    const int t    = threadIdx.x;
    const int lane = t & 63;
    const int wid  = t >> 6;
    const int wr   = wid >> 1;
    const int wc   = wid & 1;

    const ushort* Xw = Xb + (size_t)b * NROW * DIM;
    const ushort* Yw = Yb + (size_t)b * NROW * DIM;

    frag_cd acc[4][4];
    #pragma unroll
    for (int i = 0; i < 4; ++i)
        #pragma unroll
        for (int j = 0; j < 4; ++j)
            acc[i][j] = (frag_cd)0.0f;

    frag_ab ra[4], rb[4];

    auto loads = [&](int kt) {
        #pragma unroll
        for (int p = 0; p < 4; ++p) {
            const int c = t + p * 256;          // 16B chunk id, 1024 total
            const int row = c >> 3, k8 = c & 7;
            ra[p] = *(const frag_ab*)(Xw + (size_t)(row0 + row) * DIM + kt * BK + k8 * 8);
            rb[p] = *(const frag_ab*)(Yw + (size_t)(col0 + row) * DIM + kt * BK + k8 * 8);
        }
    };
    auto lwrite = [&](int buf) {
        #pragma unroll
        for (int p = 0; p < 4; ++p) {
            const int c = t + p * 256;
            const int row = c >> 3, k8 = c & 7;
            const int off = row * (BK * 2) + ((k8 ^ (row & 7)) * 16);  // XOR swizzle
            *(frag_ab*)((char*)&As[buf][0] + off) = ra[p];
            *(frag_ab*)((char*)&Bs[buf][0] + off) = rb[p];
        }
    };
    auto compute = [&](int buf) {
        #pragma unroll
        for (int kk = 0; kk < 2; ++kk) {
            frag_ab af[4], bfr[4];
            #pragma unroll
            for (int i = 0; i < 4; ++i) {
                const int row = wr * 64 + i * 16 + (lane & 15);
                const int ch  = (kk * 4 + (lane >> 4)) ^ (row & 7);
                af[i] = *(const frag_ab*)((const char*)&As[buf][0] + row * (BK * 2) + ch * 16);
            }
            #pragma unroll
            for (int j = 0; j < 4; ++j) {
                const int row = wc * 64 + j * 16 + (lane & 15);
                const int ch  = (kk * 4 + (lane >> 4)) ^ (row & 7);
                bfr[j] = *(const frag_ab*)((const char*)&Bs[buf][0] + row * (BK * 2) + ch * 16);
            }
            #pragma unroll
            for (int i = 0; i < 4; ++i)
                #pragma unroll
                for (int j = 0; j < 4; ++j)
                    acc[i][j] = __builtin_amdgcn_mfma_f32_16x16x32_bf16(af[i], bfr[j], acc[i][j], 0, 0, 0);
        }
    };

    // Pipeline: one __syncthreads per K-tile.
    //  iter kt: [loads kt+1] [compute cur] [ds_write alt] [barrier]
    //  WAR: iter-kt writes to alt vs iter-(kt-1) reads of alt -> separated by
    //       barrier at end of kt-1.  RAW: writes to alt vs reads in kt+1 ->
    //       separated by barrier at end of kt.
    loads(0);
    lwrite(0);
    __syncthreads();
    #pragma unroll
    for (int kt = 0; kt < 4; ++kt) {
        if (kt < 3) loads(kt + 1);          // global latency hides under compute
        compute(kt & 1);
        if (kt < 3) {
            lwrite((kt + 1) & 1);
            __syncthreads();
        }
    }

    // epilogue: arg = cx + cy + log2e*xy ; out = min(exp2(arg), 1)
    const float* cxb = cx + (size_t)b * NROW;
    const float* cyb = cy + (size_t)b * NROW;
    float yv[4];
    #pragma unroll
    for (int j = 0; j < 4; ++j)
        yv[j] = cyb[col0 + wc * 64 + j * 16 + (lane & 15)];

    float* outb = out + (size_t)b * NROW * NROW;
    #pragma unroll
    for (int i = 0; i < 4; ++i) {
        const int rbase = row0 + wr * 64 + i * 16 + ((lane >> 4) << 2);
        const float4 xq = *(const float4*)(cxb + rbase);
        #pragma unroll
        for (int q = 0; q < 4; ++q) {
            const float xx = (q == 0) ? xq.x : (q == 1) ? xq.y : (q == 2) ? xq.z : xq.w;
            float* orow = outb + (size_t)(rbase + q) * NROW + col0 + wc * 64 + (lane & 15);
            #pragma unroll
            for (int j = 0; j < 4; ++j) {
                float arg = fmaf(K2, acc[i][j][q], xx + yv[j]);
                __builtin_nontemporal_store(
                    fminf(__builtin_amdgcn_exp2f(arg), 1.0f), orow + j * 16);
            }
        }
    }
}

// ---------------------------------------------------------------------------
// FALLBACK (round-1, passing): used when ws_size < 16.1 MB.
__global__ __launch_bounds__(256) void rbf_norms_fb(const float* __restrict__ X,
                                                    const float* __restrict__ Y,
                                                    float* __restrict__ x2,
                                                    float* __restrict__ y2) {
    const int lane = threadIdx.x & 63;
    const int wid  = (int)(blockIdx.x * blockDim.x + threadIdx.x) >> 6;
    const int nw   = (int)(gridDim.x * blockDim.x) >> 6;
    const int total = 2 * BATCH * NROW;
    for (int row = wid; row < total; row += nw) {
        const float* src = (row < BATCH * NROW)
            ? X + (size_t)row * DIM
            : Y + (size_t)(row - BATCH * NROW) * DIM;
        float4 v = ((const float4*)src)[lane];
        float s = v.x * v.x + v.y * v.y + v.z * v.z + v.w * v.w;
        #pragma unroll
        for (int off = 32; off > 0; off >>= 1)
            s += __shfl_down(s, off, 64);
        if (lane == 0) {
            if (row < BATCH * NROW) x2[row] = s;
            else                    y2[row - BATCH * NROW] = s;
        }
    }
}

__global__ __launch_bounds__(256, 2) void rbf_main_fb(const float* __restrict__ X,
                                                      const float* __restrict__ Y,
                                                      const float* __restrict__ x2,
                                                      const float* __restrict__ y2,
                                                      float* __restrict__ out) {
    __shared__ short As[BM * BK];
    __shared__ short Bs[BN * BK];

    const int b    = blockIdx.z;
    const int row0 = blockIdx.y * BM;
    const int col0 = blockIdx.x * BN;

    const int t    = threadIdx.x;
    const int lane = t & 63;
    const int wid  = t >> 6;
    const int wr   = wid >> 1;
    const int wc   = wid & 1;

    const float* Xb = X + (size_t)b * NROW * DIM;
    const float* Yb = Y + (size_t)b * NROW * DIM;

    frag_cd acc[4][4];
    #pragma unroll
    for (int i = 0; i < 4; ++i)
        #pragma unroll
        for (int j = 0; j < 4; ++j)
            acc[i][j] = (frag_cd)0.0f;

    for (int kt = 0; kt < DIM / BK; ++kt) {
        const int k0 = kt * BK;
        float4 ra[4][2], rb[4][2];
        #pragma unroll
        for (int p = 0; p < 4; ++p) {
            const int c = t + p * 256;
            const int row = c >> 3, k8 = c & 7;
            const float4* sA = (const float4*)(Xb + (size_t)(row0 + row) * DIM + k0 + k8 * 8);
            ra[p][0] = sA[0]; ra[p][1] = sA[1];
            const float4* sB = (const float4*)(Yb + (size_t)(col0 + row) * DIM + k0 + k8 * 8);
            rb[p][0] = sB[0]; rb[p][1] = sB[1];
        }
        __syncthreads();
        #pragma unroll
        for (int p = 0; p < 4; ++p) {
            const int c = t + p * 256;
            const int row = c >> 3, k8 = c & 7;
            const int off = row * (BK * 2) + ((k8 ^ (row & 7)) * 16);
            *(frag_ab*)((char*)As + off) = pack8(ra[p][0], ra[p][1]);
            *(frag_ab*)((char*)Bs + off) = pack8(rb[p][0], rb[p][1]);
        }
        __syncthreads();
        #pragma unroll
        for (int kk = 0; kk < 2; ++kk) {
            frag_ab af[4], bfr[4];
            #pragma unroll
            for (int i = 0; i < 4; ++i) {
                const int row = wr * 64 + i * 16 + (lane & 15);
                const int ch  = (kk * 4 + (lane >> 4)) ^ (row & 7);
                af[i] = *(const frag_ab*)((const char*)As + row * (BK * 2) + ch * 16);
            }
            #pragma unroll
            for (int j = 0; j < 4; ++j) {
                const int row = wc * 64 + j * 16 + (lane & 15);
                const int ch  = (kk * 4 + (lane >> 4)) ^ (row & 7);
                bfr[j] = *(const frag_ab*)((const char*)Bs + row * (BK * 2) + ch * 16);
            }
            #pragma unroll
            for (int i = 0; i < 4; ++i)
                #pragma unroll
                for (int j = 0; j < 4; ++j)
                    acc[i][j] = __builtin_amdgcn_mfma_f32_16x16x32_bf16(af[i], bfr[j], acc[i][j], 0, 0, 0);
        }
    }

    const float* x2b = x2 + (size_t)b * NROW;
    const float* y2b = y2 + (size_t)b * NROW;
    float yv[4];
    #pragma unroll
    for (int j = 0; j < 4; ++j)
        yv[j] = y2b[col0 + wc * 64 + j * 16 + (lane & 15)];

    float* outb = out + (size_t)b * NROW * NROW;
    #pragma unroll
    for (int i = 0; i < 4; ++i) {
        const int rbase = row0 + wr * 64 + i * 16 + ((lane >> 4) << 2);
        const float4 xq = *(const float4*)(x2b + rbase);
        #pragma unroll
        for (int q = 0; q < 4; ++q) {
            const float xx = (q == 0) ? xq.x : (q == 1) ? xq.y : (q == 2) ? xq.z : xq.w;
            float* orow = outb + (size_t)(rbase + q) * NROW + col0 + wc * 64 + (lane & 15);
            #pragma unroll
            for (int j = 0; j < 4; ++j) {
                float d = xx + yv[j] - 2.0f * acc[i][j][q];
                d = fmaxf(d, 0.0f);
                orow[j * 16] = __expf(-0.5f * d);
            }
        }
    }
}

extern "C" void kernel_launch(void* const* d_in, const int* in_sizes, int n_in,
                              void* d_out, int out_size, void* d_ws, size_t ws_size,
                              hipStream_t stream) {
    const float* X = (const float*)d_in[0];
    const float* Y = (const float*)d_in[1];
    float* out = (float*)d_out;

    const size_t nrows = (size_t)BATCH * NROW;
    const size_t need  = 2 * nrows * sizeof(float) + 2 * nrows * DIM * sizeof(ushort);

    if (ws_size >= need) {
        float* cxp = (float*)d_ws;
        float* cyp = cxp + nrows;
        ushort* Xb = (ushort*)(cyp + nrows);
        ushort* Yb = Xb + nrows * DIM;
        rbf_prep<<<2048, 256, 0, stream>>>(X, Y, cxp, cyp, Xb, Yb);
        rbf_main_fast<<<4096, 256, 0, stream>>>(Xb, Yb, cxp, cyp, out);
    } else {
        float* x2 = (float*)d_ws;
        float* y2 = x2 + nrows;
        rbf_norms_fb<<<512, 256, 0, stream>>>(X, Y, x2, y2);
        rbf_main_fb<<<dim3(NROW / BN, NROW / BM, BATCH), 256, 0, stream>>>(X, Y, x2, y2, out);
    }
}